// Round 12
// baseline (75.113 us; speedup 1.0000x reference)
//
#include <hip/hip_runtime.h>
#include <hip/hip_bf16.h>

#define B_ 64
#define S_ 128
#define D_ 1024
#define O_ 1024
#define L_ 16

typedef __bf16 bf16x8 __attribute__((ext_vector_type(8)));
typedef float f32x4 __attribute__((ext_vector_type(4)));

// ws layout (bytes):
//  [0, 33554432)        W' = bf16(w), row-major [16][1024][1024]
//  [33554432, 50331648) X' = bf16(x), row-major [s:128][b:64][d:1024]  (s-major!)
//  [50331648]           npairs (int, 16-byte slot)
//  [50331664, +72*16)   pairs int4 {s0, s1, layer, 0}
//  [50332816, +32)      8 per-XCD work-queue counters
#define WS_W     0ull
#define WS_X     33554432ull
#define WS_P     50331648ull
#define WS_PAIRS (WS_P + 16ull)
#define WS_Q     (WS_PAIRS + 72ull * 16ull)
#define WS_NEED  (WS_Q + 32ull)

__device__ __forceinline__ unsigned f2bf2(float a, float b) {
    union { float f; unsigned u; } x{a}, y{b};
    unsigned lo = x.u + 0x7FFFu + ((x.u >> 16) & 1u);
    unsigned hi = y.u + 0x7FFFu + ((y.u >> 16) & 1u);
    return (lo >> 16) | (hi & 0xFFFF0000u);
}

__device__ __forceinline__ void gload16(const void* g, void* l) {
    __builtin_amdgcn_global_load_lds(
        (const __attribute__((address_space(1))) void*)g,
        (__attribute__((address_space(3))) void*)l, 16, 0, 0);
}

// ---- pass 1: linear fp32 -> bf16 cast. W row-major; x transposed to [s][b][d].
// Block 0 also builds the layer-grouped s-pairs and zeroes the queue counters.
__global__ __launch_bounds__(256) void moshi_convert(
    const float* __restrict__ x, const float* __restrict__ w,
    const int* __restrict__ lidx, unsigned char* __restrict__ ws) {
    if (blockIdx.x == 0 && threadIdx.x < 24) {
        if (threadIdx.x >= 16) {
            ((int*)(ws + WS_Q))[threadIdx.x - 16] = 0;   // queue counters
        } else {
            int t = threadIdx.x;
            int cnt[16];
            #pragma unroll 1
            for (int m = 0; m < 16; ++m) cnt[m] = 0;
            for (int s = 0; s < S_; ++s) ++cnt[lidx[s]];
            int off = 0;
            for (int m = 0; m < t; ++m) off += (cnt[m] + 1) >> 1;
            int4* pairs = (int4*)(ws + WS_PAIRS);
            int k = 0, prev = -1;
            for (int s = 0; s < S_; ++s) {
                if (lidx[s] == t) {
                    if (k & 1) pairs[off + (k >> 1)] = make_int4(prev, s, t, 0);
                    prev = s; ++k;
                }
            }
            if (k & 1) pairs[off + (k >> 1)] = make_int4(prev, prev, t, 0);
            if (t == 0) {
                int tot = 0;
                for (int m = 0; m < 16; ++m) tot += (cnt[m] + 1) >> 1;
                *(int*)(ws + WS_P) = tot;
            }
        }
    }
    unsigned i0 = blockIdx.x * 512 + threadIdx.x;
    if (blockIdx.x < 8192) {                    // W: 4194304 float4s
        const float4* src = reinterpret_cast<const float4*>(w);
        uint2* dst = reinterpret_cast<uint2*>(ws + WS_W);
        float4 v0 = src[i0];
        float4 v1 = src[i0 + 256];
        dst[i0]       = make_uint2(f2bf2(v0.x, v0.y), f2bf2(v0.z, v0.w));
        dst[i0 + 256] = make_uint2(f2bf2(v1.x, v1.y), f2bf2(v1.z, v1.w));
    } else {                                    // x: 2097152 float4s, transpose b<->s
        const float4* src = reinterpret_cast<const float4*>(x);
        uint2* dst = reinterpret_cast<uint2*>(ws + WS_X);
        unsigned j = i0 - 4194304u;
        float4 v0 = src[j];
        float4 v1 = src[j + 256];
        unsigned b0 = j >> 15, s0 = (j >> 8) & 127u, d40 = j & 255u;
        dst[(s0 * 64u + b0) * 256u + d40] =
            make_uint2(f2bf2(v0.x, v0.y), f2bf2(v0.z, v0.w));
        unsigned j1 = j + 256u;
        unsigned b1 = j1 >> 15, s1 = (j1 >> 8) & 127u, d41 = j1 & 255u;
        dst[(s1 * 64u + b1) * 256u + d41] =
            make_uint2(f2bf2(v1.x, v1.y), f2bf2(v1.z, v1.w));
    }
}

// ---- pass 2: paired GEMM, persistent blocks + per-XCD atomic work queue.
// Grid 512 (2 blocks/CU exactly). nt = blockIdx&7 is FIXED per block (each
// XCD owns one nt column: W working set 16 x 256 KB = 4 MB = one L2).
// Pair index pi popped from the XCD's counter -> per-item load balance.
// Tile M=128 (2s x 64b) x N=128, BK=64, 8 waves, 64x32/wave; gload_lds with
// source-side XOR swizzle (m173); 2-barrier K-loop (proven R6/R11 structure).
__global__ __launch_bounds__(512, 4) void moshi_gemm_pq(
    const unsigned char* __restrict__ ws, float* __restrict__ out) {
    __shared__ __align__(16) unsigned char lw[16384];
    __shared__ __align__(16) unsigned char lx[16384];
    __shared__ int item_s;

    const int nt = blockIdx.x & 7;
    int* ctr = (int*)(ws + WS_Q) + nt;
    const int np = *reinterpret_cast<const int*>(ws + WS_P);

    const int tid = threadIdx.x, lane = tid & 63, wid = tid >> 6;
    const int rowq = tid >> 3;                 // 0..63 (LDS row within half-tile)
    const int c16  = (tid & 7) << 4;
    const int csw  = c16 ^ ((rowq & 7) << 4);  // source-side swizzle
    const int wm = wid >> 2, wn = wid & 3;
    const int swz = (lane & 7) << 4;
    const int kb  = (lane >> 4) << 4;
    const int a_base = (wm * 64 + (lane & 15)) * 128 + kb;   // x rows
    const int b_base = (wn * 32 + (lane & 15)) * 128 + kb;   // W rows

    const unsigned char* wbase = ws + WS_W + ((size_t)(nt * 128 + rowq) << 11) + csw;

    for (;;) {
        if (tid == 0) item_s = atomicAdd(ctr, 1);
        __syncthreads();
        const int pi = item_s;
        __syncthreads();                       // all read before next pop write
        if (pi >= 72) break;                   // block-uniform
        if (pi >= np) continue;                // padded slot, cheap skip

        const int4 pr = *reinterpret_cast<const int4*>(ws + WS_PAIRS + 16ull * pi);
        const int s0 = pr.x, s1 = pr.y, l = pr.z;

        const unsigned char* wsrc0 = wbase + ((size_t)(l * 1024) << 11);
        const unsigned char* wsrc1 = wsrc0 + ((size_t)64 << 11);
        const unsigned char* xsrc0 = ws + WS_X + ((size_t)(s0 * 64 + rowq) << 11) + csw;
        const unsigned char* xsrc1 = ws + WS_X + ((size_t)(s1 * 64 + rowq) << 11) + csw;

        f32x4 acc[4][2];
        #pragma unroll
        for (int i = 0; i < 4; ++i)
            #pragma unroll
            for (int j = 0; j < 2; ++j) acc[i][j] = (f32x4)0.0f;

        #pragma unroll 1
        for (int kt = 0; kt < 16; ++kt) {
            __syncthreads();                   // prior reads of LDS done
            gload16(wsrc0 + kt * 128, lw + tid * 16);
            gload16(wsrc1 + kt * 128, lw + tid * 16 + 8192);
            gload16(xsrc0 + kt * 128, lx + tid * 16);
            gload16(xsrc1 + kt * 128, lx + tid * 16 + 8192);
            __syncthreads();                   // stage visible
            #pragma unroll
            for (int kk = 0; kk < 2; ++kk) {
                bf16x8 af[4], bfr[2];
                #pragma unroll
                for (int mi = 0; mi < 4; ++mi)
                    af[mi] = *reinterpret_cast<const bf16x8*>(
                        lx + (((a_base + kk * 64) ^ swz) + mi * 2048));
                #pragma unroll
                for (int ni = 0; ni < 2; ++ni)
                    bfr[ni] = *reinterpret_cast<const bf16x8*>(
                        lw + (((b_base + kk * 64) ^ swz) + ni * 2048));
                #pragma unroll
                for (int mi = 0; mi < 4; ++mi)
                    #pragma unroll
                    for (int ni = 0; ni < 2; ++ni)
                        acc[mi][ni] = __builtin_amdgcn_mfma_f32_16x16x32_bf16(
                            af[mi], bfr[ni], acc[mi][ni], 0, 0, 0);
            }
        }

        // epilogue: C/D col = lane&15 (o), row = (lane>>4)*4 + reg (b)
        const int s_sel = wm ? s1 : s0;
        const int col0 = nt * 128 + wn * 32 + (lane & 15);
        const int r0 = (lane >> 4) << 2;
        #pragma unroll
        for (int mi = 0; mi < 4; ++mi)
            #pragma unroll
            for (int ni = 0; ni < 2; ++ni)
                #pragma unroll
                for (int r = 0; r < 4; ++r) {
                    int b = mi * 16 + r0 + r;
                    out[((size_t)b * S_ + s_sel) * O_ + col0 + ni * 16] = acc[mi][ni][r];
                }
    }
}

// ---- fallback (round-1 kernel) if ws is too small ----
__global__ __launch_bounds__(256) void moshi_flin_fallback(
    const float* __restrict__ x, const int* __restrict__ lidx,
    const float* __restrict__ w, float* __restrict__ out) {
    __shared__ __align__(16) unsigned char lxs[64 * 128];
    __shared__ __align__(16) unsigned char lws[128 * 128];
    const int bid = blockIdx.x;
    const int s = bid >> 3, n0 = (bid & 7) << 7;
    const int tid = threadIdx.x, lane = tid & 63, wid = tid >> 6;
    const int idx = lidx[s];
    const float* wb = w + (size_t)idx * O_ * D_ + (size_t)n0 * D_;
    const float* xb = x + (size_t)s * D_;
    const int swz = (lane & 7) << 4;
    const int kb = (lane >> 4) << 4;
    const int a_base = (lane & 15) * 128 + kb;
    const int b_base = (wid * 32 + (lane & 15)) * 128 + kb;
    f32x4 acc[4][2];
    #pragma unroll
    for (int i = 0; i < 4; ++i)
        #pragma unroll
        for (int j = 0; j < 2; ++j) acc[i][j] = (f32x4)0.0f;
    for (int kt = 0; kt < D_; kt += 64) {
        __syncthreads();
        #pragma unroll
        for (int p = 0; p < 4; ++p) {
            int f = tid + p * 256, row = f >> 4, cc = (f & 15) << 2;
            const float4 v = *reinterpret_cast<const float4*>(
                xb + (size_t)row * (S_ * D_) + kt + cc);
            uint2 pk = { f2bf2(v.x, v.y), f2bf2(v.z, v.w) };
            *reinterpret_cast<uint2*>(&lxs[(row * 128 + cc * 2) ^ ((row & 7) << 4)]) = pk;
        }
        #pragma unroll
        for (int p = 0; p < 8; ++p) {
            int f = tid + p * 256, row = f >> 4, cc = (f & 15) << 2;
            const float4 v = *reinterpret_cast<const float4*>(
                wb + (size_t)row * D_ + kt + cc);
            uint2 pk = { f2bf2(v.x, v.y), f2bf2(v.z, v.w) };
            *reinterpret_cast<uint2*>(&lws[(row * 128 + cc * 2) ^ ((row & 7) << 4)]) = pk;
        }
        __syncthreads();
        #pragma unroll
        for (int kk = 0; kk < 2; ++kk) {
            bf16x8 af[4], bfr[2];
            #pragma unroll
            for (int mi = 0; mi < 4; ++mi)
                af[mi] = *reinterpret_cast<const bf16x8*>(
                    &lxs[(((a_base + kk * 64) ^ swz) + mi * 2048)]);
            #pragma unroll
            for (int ni = 0; ni < 2; ++ni)
                bfr[ni] = *reinterpret_cast<const bf16x8*>(
                    &lws[(((b_base + kk * 64) ^ swz) + ni * 2048)]);
            #pragma unroll
            for (int mi = 0; mi < 4; ++mi)
                #pragma unroll
                for (int ni = 0; ni < 2; ++ni)
                    acc[mi][ni] = __builtin_amdgcn_mfma_f32_16x16x32_bf16(
                        af[mi], bfr[ni], acc[mi][ni], 0, 0, 0);
        }
    }
    float* ob = out + (size_t)s * O_ + n0 + wid * 32 + (lane & 15);
    const int r0 = (lane >> 4) << 2;
    #pragma unroll
    for (int mi = 0; mi < 4; ++mi)
        #pragma unroll
        for (int ni = 0; ni < 2; ++ni)
            #pragma unroll
            for (int r = 0; r < 4; ++r) {
                int b = mi * 16 + r0 + r;
                ob[(size_t)b * (S_ * O_) + ni * 16] = acc[mi][ni][r];
            }
}

extern "C" void kernel_launch(void* const* d_in, const int* in_sizes, int n_in,
                              void* d_out, int out_size, void* d_ws, size_t ws_size,
                              hipStream_t stream) {
    const float* x  = (const float*)d_in[0];
    const int* lidx = (const int*)d_in[1];
    const float* w  = (const float*)d_in[2];
    float* out      = (float*)d_out;

    if (ws_size < WS_NEED) {
        moshi_flin_fallback<<<dim3(128 * 8), dim3(256), 0, stream>>>(x, lidx, w, out);
        return;
    }
    unsigned char* ws = (unsigned char*)d_ws;
    moshi_convert<<<dim3(12288), dim3(256), 0, stream>>>(x, w, lidx, ws);
    // persistent: 512 blocks (2/CU), per-XCD queue over 72 pair slots each
    moshi_gemm_pq<<<dim3(512), dim3(512), 0, stream>>>(ws, out);
}